// Round 3
// baseline (583.366 us; speedup 1.0000x reference)
//
#include <hip/hip_runtime.h>
#include <hip/hip_bf16.h>

typedef __bf16 bf16_t;
typedef __attribute__((ext_vector_type(8))) __bf16 bf16x8;
typedef __attribute__((ext_vector_type(4))) __bf16 bf16x4;
typedef __attribute__((ext_vector_type(4))) float floatx4;
typedef __attribute__((ext_vector_type(4))) int intx4;

#define NN 8192
#define FIN 256
#define FOUT 64
#define GAT_ALPHA 0.2f
#define JHALF (NN / 2)

// ---------------------------------------------------------------------------
// Kernel A: h = input @ W (fp32 in -> bf16 MFMA), store hT (bf16 [64][8192])
// and per-row scalars s1,s2 (fp32), E=exp(s), F=exp(0.2 s).
// ---------------------------------------------------------------------------
__global__ __launch_bounds__(256) void gat_h_kernel(
    const float* __restrict__ input,    // [8192][256] fp32
    const float* __restrict__ W,        // [256][64] fp32
    const float* __restrict__ a,        // [128] fp32
    bf16_t* __restrict__ hT,            // [64][8192] bf16 (internal)
    float* __restrict__ s1g, float* __restrict__ e1g, float* __restrict__ f1g,
    float* __restrict__ s2g, float* __restrict__ e2g, float* __restrict__ f2g)
{
    alignas(16) __shared__ bf16_t in_lds[32][264];  // input tile, K contiguous
    alignas(16) __shared__ bf16_t wt_lds[64][264];  // W transposed [f][k]
    __shared__ float h_lds[32][65];                 // h tile fp32 for s1/s2

    const int t  = threadIdx.x;
    const int i0 = blockIdx.x * 32;

    // stage input tile [32][256]: fp32 float4 loads -> bf16x4 LDS stores
    #pragma unroll
    for (int v = 0; v < 8; v++) {
        int u  = v * 256 + t;          // 0..2047
        int i  = u >> 6;               // 0..31
        int k4 = (u & 63) * 4;         // 0..252
        floatx4 x = *(const floatx4*)(input + (size_t)(i0 + i) * FIN + k4);
        bf16x4 b;
        #pragma unroll
        for (int e = 0; e < 4; e++) b[e] = (bf16_t)x[e];
        *(bf16x4*)(&in_lds[i][k4]) = b;
    }
    // stage W transposed: read [k][f] coalesced fp32, write wt_lds[f][k] bf16
    #pragma unroll
    for (int v = 0; v < 16; v++) {
        int u  = v * 256 + t;          // 0..4095
        int k  = u >> 4;               // 0..255
        int f4 = (u & 15) * 4;         // 0..60
        floatx4 wv = *(const floatx4*)(W + k * FOUT + f4);
        #pragma unroll
        for (int e = 0; e < 4; e++) wt_lds[f4 + e][k] = (bf16_t)wv[e];
    }
    __syncthreads();

    const int wave = t >> 6;
    const int lane = t & 63;
    const int i16  = (wave & 1) * 16;
    const int f32  = (wave >> 1) * 32;
    const int lm   = lane & 15;
    const int lq   = lane >> 4;

    floatx4 acc0 = {0.f, 0.f, 0.f, 0.f};
    floatx4 acc1 = {0.f, 0.f, 0.f, 0.f};
    #pragma unroll
    for (int ks = 0; ks < 8; ks++) {
        int ko = ks * 32 + lq * 8;
        bf16x8 af = *(const bf16x8*)(&in_lds[i16 + lm][ko]);
        bf16x8 b0 = *(const bf16x8*)(&wt_lds[f32 + lm][ko]);
        bf16x8 b1 = *(const bf16x8*)(&wt_lds[f32 + 16 + lm][ko]);
        acc0 = __builtin_amdgcn_mfma_f32_16x16x32_bf16(af, b0, acc0, 0, 0, 0);
        acc1 = __builtin_amdgcn_mfma_f32_16x16x32_bf16(af, b1, acc1, 0, 0, 0);
    }

    // store hT (bf16): C layout col=lane&15 (=f), row=lq*4+r (=i within 16)
    #pragma unroll
    for (int c = 0; c < 2; c++) {
        floatx4 acc = c ? acc1 : acc0;
        int f  = f32 + c * 16 + lm;
        int ib = i0 + i16 + lq * 4;
        bf16x4 hp;
        #pragma unroll
        for (int r = 0; r < 4; r++) hp[r] = (bf16_t)acc[r];
        *(bf16x4*)(hT + (size_t)f * NN + ib) = hp;
    }
    // fp32 h tile into LDS for s1/s2
    #pragma unroll
    for (int c = 0; c < 2; c++) {
        floatx4 acc = c ? acc1 : acc0;
        #pragma unroll
        for (int r = 0; r < 4; r++)
            h_lds[i16 + lq * 4 + r][f32 + c * 16 + lm] = acc[r];
    }
    __syncthreads();

    if (t < 64) {
        int r   = t & 31;
        int sel = t >> 5;                       // 0 -> a1/s1, 1 -> a2/s2
        const float* av = a + sel * FOUT;
        float s = 0.f;
        #pragma unroll 8
        for (int f = 0; f < FOUT; f++) s += h_lds[r][f] * av[f];
        int gi = i0 + r;
        float E = expf(s);
        float F = expf(GAT_ALPHA * s);
        if (sel == 0) { s1g[gi] = s; e1g[gi] = E; f1g[gi] = F; }
        else          { s2g[gi] = s; e2g[gi] = E; f2g[gi] = F; }
    }
}

// ---------------------------------------------------------------------------
// Kernel B: fused masked softmax + aggregation over one j-half per block.
// Grid (256 row-blocks, 2 j-halves) = 512 blocks -> 2 blocks/CU for
// cross-block latency hiding. Emits fp32 partial acc + partial rowsum.
// ---------------------------------------------------------------------------
#define LOAD_CHUNK(J0, ADJV, HV, S2V, E2V, F2V)                                \
    {                                                                          \
        S2V = *(const floatx4*)(s2g + (J0) + 4 * tj);                          \
        E2V = *(const floatx4*)(e2g + (J0) + 4 * tj);                          \
        F2V = *(const floatx4*)(f2g + (J0) + 4 * tj);                          \
        _Pragma("unroll")                                                      \
        for (int it = 0; it < 8; it++)                                         \
            ADJV[it] = *(const intx4*)(adj +                                   \
                (size_t)(i0 + it * 4 + ti) * NN + (J0) + 4 * tj);              \
        _Pragma("unroll")                                                      \
        for (int u = 0; u < 8; u++) {                                          \
            int f  = (u * 256 + t) >> 5;                                       \
            int j8 = ((u * 256 + t) & 31) * 8;                                 \
            HV[u] = *(const bf16x8*)(hT + (size_t)f * NN + (J0) + j8);         \
        }                                                                      \
    }

#define CONSUME_CHUNK(ADJV, HV, S2V, E2V, F2V)                                 \
    {                                                                          \
        _Pragma("unroll")                                                      \
        for (int it = 0; it < 8; it++) {                                       \
            int r = it * 4 + ti;                                               \
            float s1r = s1_l[r], E1 = e1_l[r], F1 = f1_l[r];                   \
            bf16x4 wq;                                                         \
            float sum = 0.f;                                                   \
            _Pragma("unroll")                                                  \
            for (int e = 0; e < 4; e++) {                                      \
                bool pos = (s1r + S2V[e]) > 0.f;                               \
                float wv = (ADJV[it][e] > 0)                                   \
                               ? (pos ? E1 * E2V[e] : F1 * F2V[e]) : 0.f;      \
                bf16_t wb = (bf16_t)wv;                                        \
                wq[e] = wb;                                                    \
                sum += (float)wb;                                              \
            }                                                                  \
            rowsum[it] += sum;                                                 \
            *(bf16x4*)(&w_lds[r][4 * tj]) = wq;                                \
        }                                                                      \
        _Pragma("unroll")                                                      \
        for (int u = 0; u < 8; u++) {                                          \
            int f  = (u * 256 + t) >> 5;                                       \
            int j8 = ((u * 256 + t) & 31) * 8;                                 \
            *(bf16x8*)(&ht_lds[f][j8]) = HV[u];                                \
        }                                                                      \
    }

#define MFMA_CHUNK()                                                           \
    {                                                                          \
        _Pragma("unroll")                                                      \
        for (int ks = 0; ks < 8; ks++) {                                       \
            int ko = ks * 32 + lq * 8;                                         \
            bf16x8 af = *(const bf16x8*)(&w_lds[i16 + lm][ko]);                \
            bf16x8 b0 = *(const bf16x8*)(&ht_lds[f32 + lm][ko]);               \
            bf16x8 b1 = *(const bf16x8*)(&ht_lds[f32 + 16 + lm][ko]);          \
            acc0 = __builtin_amdgcn_mfma_f32_16x16x32_bf16(af, b0, acc0,0,0,0);\
            acc1 = __builtin_amdgcn_mfma_f32_16x16x32_bf16(af, b1, acc1,0,0,0);\
        }                                                                      \
    }

__global__ __launch_bounds__(256, 2) void gat_att_kernel(
    const int* __restrict__ adj,        // [8192][8192] int32
    const bf16_t* __restrict__ hT,      // [64][8192] bf16
    const float* __restrict__ s1g, const float* __restrict__ e1g,
    const float* __restrict__ f1g,
    const float* __restrict__ s2g, const float* __restrict__ e2g,
    const float* __restrict__ f2g,
    float* __restrict__ pacc,           // [2][8192][64] fp32 partial acc
    float* __restrict__ prs)            // [2][8192] fp32 partial rowsum
{
    alignas(16) __shared__ bf16_t w_lds[32][264];
    alignas(16) __shared__ bf16_t ht_lds[64][264];
    __shared__ float part[32][66];
    __shared__ float s1_l[32], e1_l[32], f1_l[32];

    const int t     = threadIdx.x;
    const int i0    = blockIdx.x * 32;
    const int half  = blockIdx.y;       // 0 or 1
    const int jbase = half * JHALF;
    const int tj    = t & 63;           // j-group 0..63 (4 j's each)
    const int ti    = t >> 6;           // 0..3

    if (t < 32) {
        s1_l[t] = s1g[i0 + t];
        e1_l[t] = e1g[i0 + t];
        f1_l[t] = f1g[i0 + t];
    }
    __syncthreads();

    const int wave = t >> 6;
    const int lane = t & 63;
    const int i16  = (wave & 1) * 16;
    const int f32  = (wave >> 1) * 32;
    const int lm   = lane & 15;
    const int lq   = lane >> 4;

    floatx4 acc0 = {0.f, 0.f, 0.f, 0.f};
    floatx4 acc1 = {0.f, 0.f, 0.f, 0.f};
    float rowsum[8];
    #pragma unroll
    for (int r = 0; r < 8; r++) rowsum[r] = 0.f;

    intx4  adjA[8], adjB[8];
    bf16x8 hvA[8], hvB[8];
    floatx4 s2A, e2A, f2A, s2B, e2B, f2B;

    LOAD_CHUNK(jbase, adjA, hvA, s2A, e2A, f2A);

    for (int j0 = jbase; j0 < jbase + JHALF; j0 += 512) {
        __syncthreads();                    // prev MFMA done reading LDS
        CONSUME_CHUNK(adjA, hvA, s2A, e2A, f2A);
        LOAD_CHUNK(j0 + 256, adjB, hvB, s2B, e2B, f2B);
        __syncthreads();
        MFMA_CHUNK();

        __syncthreads();
        CONSUME_CHUNK(adjB, hvB, s2B, e2B, f2B);
        if (j0 + 512 < jbase + JHALF)
            LOAD_CHUNK(j0 + 512, adjA, hvA, s2A, e2A, f2A);
        __syncthreads();
        MFMA_CHUNK();
    }

    // ---- partial rowsum reduction -> prs[half][i0..i0+31] ----
    #pragma unroll
    for (int it = 0; it < 8; it++) part[it * 4 + ti][tj] = rowsum[it];
    __syncthreads();
    if (t < 32) {
        float s = 0.f;
        #pragma unroll 8
        for (int k = 0; k < 64; k++) s += part[t][k];
        prs[half * NN + i0 + t] = s;
    }

    // ---- write fp32 partial acc ----
    float* pa = pacc + (size_t)half * NN * FOUT;
    #pragma unroll
    for (int c = 0; c < 2; c++) {
        floatx4 acc = c ? acc1 : acc0;
        int f = f32 + c * 16 + lm;
        #pragma unroll
        for (int r = 0; r < 4; r++) {
            int i = i16 + lq * 4 + r;
            pa[(size_t)(i0 + i) * FOUT + f] = acc[r];
        }
    }
}

// ---------------------------------------------------------------------------
// Kernel C: combine halves, normalize, ELU, store fp32 output.
// ---------------------------------------------------------------------------
__global__ __launch_bounds__(256) void gat_combine_kernel(
    const float* __restrict__ pacc,     // [2][8192][64]
    const float* __restrict__ prs,      // [2][8192]
    float* __restrict__ out)            // [8192][64]
{
    int idx = blockIdx.x * 256 + threadIdx.x;   // one float4 group each
    int i   = idx >> 4;                          // row (16 groups per row)
    floatx4 a0 = *(const floatx4*)(pacc + (size_t)idx * 4);
    floatx4 a1 = *(const floatx4*)(pacc + (size_t)NN * FOUT + (size_t)idx * 4);
    float rs   = prs[i] + prs[NN + i];
    float rinv = (rs > 0.f) ? 1.0f / rs : 0.f;
    floatx4 r;
    #pragma unroll
    for (int e = 0; e < 4; e++) {
        float x = (a0[e] + a1[e]) * rinv;
        r[e] = (x > 0.f) ? x : (expf(x) - 1.0f);
    }
    *(floatx4*)(out + (size_t)idx * 4) = r;
}

// ---------------------------------------------------------------------------
extern "C" void kernel_launch(void* const* d_in, const int* in_sizes, int n_in,
                              void* d_out, int out_size, void* d_ws, size_t ws_size,
                              hipStream_t stream) {
    const float* input = (const float*)d_in[0];     // [8192][256] fp32
    const int*   adj   = (const int*)d_in[1];       // [8192][8192] int32
    const float* W     = (const float*)d_in[2];     // [256][64] fp32
    const float* a     = (const float*)d_in[3];     // [128] fp32
    float*       out   = (float*)d_out;             // [8192][64] fp32

    char* ws = (char*)d_ws;
    bf16_t* hT  = (bf16_t*)ws;                      // 64*8192*2 = 1 MiB
    float*  s1g = (float*)(ws + (1 << 20));
    float*  e1g = s1g + NN;
    float*  f1g = e1g + NN;
    float*  s2g = f1g + NN;
    float*  e2g = s2g + NN;
    float*  f2g = e2g + NN;
    float*  pacc = f2g + NN;                        // 2*8192*64 fp32 = 4 MiB
    float*  prs  = pacc + 2 * NN * FOUT;            // 2*8192 fp32

    gat_h_kernel<<<NN / 32, 256, 0, stream>>>(input, W, a, hT,
                                              s1g, e1g, f1g, s2g, e2g, f2g);
    dim3 gridB(NN / 32, 2);
    gat_att_kernel<<<gridB, 256, 0, stream>>>(adj, hT,
                                              s1g, e1g, f1g, s2g, e2g, f2g,
                                              pacc, prs);
    gat_combine_kernel<<<NN * FOUT / 4 / 256, 256, 0, stream>>>(pacc, prs, out);
}

// Round 4
// 390.449 us; speedup vs baseline: 1.4941x; 1.4941x over previous
//
#include <hip/hip_runtime.h>
#include <hip/hip_bf16.h>

typedef __bf16 bf16_t;
typedef __attribute__((ext_vector_type(8))) __bf16 bf16x8;
typedef __attribute__((ext_vector_type(4))) __bf16 bf16x4;
typedef __attribute__((ext_vector_type(4))) float floatx4;
typedef __attribute__((ext_vector_type(4))) int intx4;

#define NN 8192
#define FIN 256
#define FOUT 64
#define GAT_ALPHA 0.2f
#define JHALF (NN / 2)

// ---------------------------------------------------------------------------
// Kernel A: h = input @ W (fp32 in -> bf16 MFMA), store hT (bf16 [64][8192])
// and per-row scalars s1,s2 (fp32), E=exp(s), F=exp(0.2 s).
// ---------------------------------------------------------------------------
__global__ __launch_bounds__(256) void gat_h_kernel(
    const float* __restrict__ input,    // [8192][256] fp32
    const float* __restrict__ W,        // [256][64] fp32
    const float* __restrict__ a,        // [128] fp32
    bf16_t* __restrict__ hT,            // [64][8192] bf16 (internal)
    float* __restrict__ s1g, float* __restrict__ e1g, float* __restrict__ f1g,
    float* __restrict__ s2g, float* __restrict__ e2g, float* __restrict__ f2g)
{
    alignas(16) __shared__ bf16_t in_lds[32][264];  // input tile, K contiguous
    alignas(16) __shared__ bf16_t wt_lds[64][264];  // W transposed [f][k]
    __shared__ float h_lds[32][65];                 // h tile fp32 for s1/s2

    const int t  = threadIdx.x;
    const int i0 = blockIdx.x * 32;

    // stage input tile [32][256]: fp32 float4 loads -> bf16x4 LDS stores
    #pragma unroll
    for (int v = 0; v < 8; v++) {
        int u  = v * 256 + t;          // 0..2047
        int i  = u >> 6;               // 0..31
        int k4 = (u & 63) * 4;         // 0..252
        floatx4 x = *(const floatx4*)(input + (size_t)(i0 + i) * FIN + k4);
        bf16x4 b;
        #pragma unroll
        for (int e = 0; e < 4; e++) b[e] = (bf16_t)x[e];
        *(bf16x4*)(&in_lds[i][k4]) = b;
    }
    // stage W transposed: read [k][f] coalesced fp32, write wt_lds[f][k] bf16
    #pragma unroll
    for (int v = 0; v < 16; v++) {
        int u  = v * 256 + t;          // 0..4095
        int k  = u >> 4;               // 0..255
        int f4 = (u & 15) * 4;         // 0..60
        floatx4 wv = *(const floatx4*)(W + k * FOUT + f4);
        #pragma unroll
        for (int e = 0; e < 4; e++) wt_lds[f4 + e][k] = (bf16_t)wv[e];
    }
    __syncthreads();

    const int wave = t >> 6;
    const int lane = t & 63;
    const int i16  = (wave & 1) * 16;
    const int f32  = (wave >> 1) * 32;
    const int lm   = lane & 15;
    const int lq   = lane >> 4;

    floatx4 acc0 = {0.f, 0.f, 0.f, 0.f};
    floatx4 acc1 = {0.f, 0.f, 0.f, 0.f};
    #pragma unroll
    for (int ks = 0; ks < 8; ks++) {
        int ko = ks * 32 + lq * 8;
        bf16x8 af = *(const bf16x8*)(&in_lds[i16 + lm][ko]);
        bf16x8 b0 = *(const bf16x8*)(&wt_lds[f32 + lm][ko]);
        bf16x8 b1 = *(const bf16x8*)(&wt_lds[f32 + 16 + lm][ko]);
        acc0 = __builtin_amdgcn_mfma_f32_16x16x32_bf16(af, b0, acc0, 0, 0, 0);
        acc1 = __builtin_amdgcn_mfma_f32_16x16x32_bf16(af, b1, acc1, 0, 0, 0);
    }

    // store hT (bf16): C layout col=lane&15 (=f), row=lq*4+r (=i within 16)
    #pragma unroll
    for (int c = 0; c < 2; c++) {
        floatx4 acc = c ? acc1 : acc0;
        int f  = f32 + c * 16 + lm;
        int ib = i0 + i16 + lq * 4;
        bf16x4 hp;
        #pragma unroll
        for (int r = 0; r < 4; r++) hp[r] = (bf16_t)acc[r];
        *(bf16x4*)(hT + (size_t)f * NN + ib) = hp;
    }
    // fp32 h tile into LDS for s1/s2
    #pragma unroll
    for (int c = 0; c < 2; c++) {
        floatx4 acc = c ? acc1 : acc0;
        #pragma unroll
        for (int r = 0; r < 4; r++)
            h_lds[i16 + lq * 4 + r][f32 + c * 16 + lm] = acc[r];
    }
    __syncthreads();

    if (t < 64) {
        int r   = t & 31;
        int sel = t >> 5;                       // 0 -> a1/s1, 1 -> a2/s2
        const float* av = a + sel * FOUT;
        float s = 0.f;
        #pragma unroll 8
        for (int f = 0; f < FOUT; f++) s += h_lds[r][f] * av[f];
        int gi = i0 + r;
        float E = expf(s);
        float F = expf(GAT_ALPHA * s);
        if (sel == 0) { s1g[gi] = s; e1g[gi] = E; f1g[gi] = F; }
        else          { s2g[gi] = s; e2g[gi] = E; f2g[gi] = F; }
    }
}

// ---------------------------------------------------------------------------
// Kernel B: fused masked softmax + aggregation over one j-half per block.
// Grid (256, 2) = 512 blocks -> 2 blocks/CU (LDS-limited). SINGLE register
// buffer: consume chunk n -> regs dead -> issue chunk n+1 loads -> barrier
// -> MFMA chunk n. Peak live VGPRs ~110: no spills at any cap >= 128.
// ---------------------------------------------------------------------------
#define LOAD_CHUNK(J0)                                                         \
    {                                                                          \
        s2v = *(const floatx4*)(s2g + (J0) + 4 * tj);                          \
        e2v = *(const floatx4*)(e2g + (J0) + 4 * tj);                          \
        f2v = *(const floatx4*)(f2g + (J0) + 4 * tj);                          \
        _Pragma("unroll")                                                      \
        for (int it = 0; it < 8; it++)                                         \
            adjv[it] = *(const intx4*)(adj +                                   \
                (size_t)(i0 + it * 4 + ti) * NN + (J0) + 4 * tj);              \
        _Pragma("unroll")                                                      \
        for (int u = 0; u < 8; u++) {                                          \
            int f  = (u * 256 + t) >> 5;                                       \
            int j8 = ((u * 256 + t) & 31) * 8;                                 \
            hv[u] = *(const bf16x8*)(hT + (size_t)f * NN + (J0) + j8);         \
        }                                                                      \
    }

#define CONSUME_CHUNK()                                                        \
    {                                                                          \
        _Pragma("unroll")                                                      \
        for (int it = 0; it < 8; it++) {                                       \
            int r = it * 4 + ti;                                               \
            float s1r = s1_l[r], E1 = e1_l[r], F1 = f1_l[r];                   \
            bf16x4 wq;                                                         \
            float sum = 0.f;                                                   \
            _Pragma("unroll")                                                  \
            for (int e = 0; e < 4; e++) {                                      \
                bool pos = (s1r + s2v[e]) > 0.f;                               \
                float wv = (adjv[it][e] > 0)                                   \
                               ? (pos ? E1 * e2v[e] : F1 * f2v[e]) : 0.f;      \
                bf16_t wb = (bf16_t)wv;                                        \
                wq[e] = wb;                                                    \
                sum += (float)wb;                                              \
            }                                                                  \
            rowsum[it] += sum;                                                 \
            *(bf16x4*)(&w_lds[r][4 * tj]) = wq;                                \
        }                                                                      \
        _Pragma("unroll")                                                      \
        for (int u = 0; u < 8; u++) {                                          \
            int f  = (u * 256 + t) >> 5;                                       \
            int j8 = ((u * 256 + t) & 31) * 8;                                 \
            *(bf16x8*)(&ht_lds[f][j8]) = hv[u];                                \
        }                                                                      \
    }

#define MFMA_CHUNK()                                                           \
    {                                                                          \
        _Pragma("unroll")                                                      \
        for (int ks = 0; ks < 8; ks++) {                                       \
            int ko = ks * 32 + lq * 8;                                         \
            bf16x8 af = *(const bf16x8*)(&w_lds[i16 + lm][ko]);                \
            bf16x8 b0 = *(const bf16x8*)(&ht_lds[f32 + lm][ko]);               \
            bf16x8 b1 = *(const bf16x8*)(&ht_lds[f32 + 16 + lm][ko]);          \
            acc0 = __builtin_amdgcn_mfma_f32_16x16x32_bf16(af, b0, acc0,0,0,0);\
            acc1 = __builtin_amdgcn_mfma_f32_16x16x32_bf16(af, b1, acc1,0,0,0);\
        }                                                                      \
    }

__global__ __launch_bounds__(256, 2) void gat_att_kernel(
    const int* __restrict__ adj,        // [8192][8192] int32
    const bf16_t* __restrict__ hT,      // [64][8192] bf16
    const float* __restrict__ s1g, const float* __restrict__ e1g,
    const float* __restrict__ f1g,
    const float* __restrict__ s2g, const float* __restrict__ e2g,
    const float* __restrict__ f2g,
    float* __restrict__ pacc,           // [2][8192][64] fp32 partial acc
    float* __restrict__ prs)            // [2][8192] fp32 partial rowsum
{
    alignas(16) __shared__ bf16_t w_lds[32][264];
    alignas(16) __shared__ bf16_t ht_lds[64][264];
    __shared__ float part[32][66];
    __shared__ float s1_l[32], e1_l[32], f1_l[32];

    const int t     = threadIdx.x;
    const int i0    = blockIdx.x * 32;
    const int half  = blockIdx.y;       // 0 or 1
    const int jbase = half * JHALF;
    const int tj    = t & 63;           // j-group 0..63 (4 j's each)
    const int ti    = t >> 6;           // 0..3

    if (t < 32) {
        s1_l[t] = s1g[i0 + t];
        e1_l[t] = e1g[i0 + t];
        f1_l[t] = f1g[i0 + t];
    }

    const int wave = t >> 6;
    const int lane = t & 63;
    const int i16  = (wave & 1) * 16;
    const int f32  = (wave >> 1) * 32;
    const int lm   = lane & 15;
    const int lq   = lane >> 4;

    floatx4 acc0 = {0.f, 0.f, 0.f, 0.f};
    floatx4 acc1 = {0.f, 0.f, 0.f, 0.f};
    float rowsum[8];
    #pragma unroll
    for (int r = 0; r < 8; r++) rowsum[r] = 0.f;

    intx4   adjv[8];
    bf16x8  hv[8];
    floatx4 s2v, e2v, f2v;

    LOAD_CHUNK(jbase);

    for (int j0 = jbase; j0 < jbase + JHALF; j0 += 256) {
        __syncthreads();                // prev MFMA done reading LDS; s1_l ready
        CONSUME_CHUNK();                // regs -> LDS, rowsum
        if (j0 + 256 < jbase + JHALF)
            LOAD_CHUNK(j0 + 256);       // regs dead after consume: refill
        __syncthreads();                // LDS writes visible
        MFMA_CHUNK();
    }

    // ---- partial rowsum reduction -> prs[half][i0..i0+31] ----
    #pragma unroll
    for (int it = 0; it < 8; it++) part[it * 4 + ti][tj] = rowsum[it];
    __syncthreads();
    if (t < 32) {
        float s = 0.f;
        #pragma unroll 8
        for (int k = 0; k < 64; k++) s += part[t][k];
        prs[half * NN + i0 + t] = s;
    }

    // ---- write fp32 partial acc ----
    float* pa = pacc + (size_t)half * NN * FOUT;
    #pragma unroll
    for (int c = 0; c < 2; c++) {
        floatx4 acc = c ? acc1 : acc0;
        int f = f32 + c * 16 + lm;
        #pragma unroll
        for (int r = 0; r < 4; r++) {
            int i = i16 + lq * 4 + r;
            pa[(size_t)(i0 + i) * FOUT + f] = acc[r];
        }
    }
}

// ---------------------------------------------------------------------------
// Kernel C: combine halves, normalize, ELU, store fp32 output.
// ---------------------------------------------------------------------------
__global__ __launch_bounds__(256) void gat_combine_kernel(
    const float* __restrict__ pacc,     // [2][8192][64]
    const float* __restrict__ prs,      // [2][8192]
    float* __restrict__ out)            // [8192][64]
{
    int idx = blockIdx.x * 256 + threadIdx.x;   // one float4 group each
    int i   = idx >> 4;                          // row (16 groups per row)
    floatx4 a0 = *(const floatx4*)(pacc + (size_t)idx * 4);
    floatx4 a1 = *(const floatx4*)(pacc + (size_t)NN * FOUT + (size_t)idx * 4);
    float rs   = prs[i] + prs[NN + i];
    float rinv = (rs > 0.f) ? 1.0f / rs : 0.f;
    floatx4 r;
    #pragma unroll
    for (int e = 0; e < 4; e++) {
        float x = (a0[e] + a1[e]) * rinv;
        r[e] = (x > 0.f) ? x : (expf(x) - 1.0f);
    }
    *(floatx4*)(out + (size_t)idx * 4) = r;
}

// ---------------------------------------------------------------------------
extern "C" void kernel_launch(void* const* d_in, const int* in_sizes, int n_in,
                              void* d_out, int out_size, void* d_ws, size_t ws_size,
                              hipStream_t stream) {
    const float* input = (const float*)d_in[0];     // [8192][256] fp32
    const int*   adj   = (const int*)d_in[1];       // [8192][8192] int32
    const float* W     = (const float*)d_in[2];     // [256][64] fp32
    const float* a     = (const float*)d_in[3];     // [128] fp32
    float*       out   = (float*)d_out;             // [8192][64] fp32

    char* ws = (char*)d_ws;
    bf16_t* hT  = (bf16_t*)ws;                      // 64*8192*2 = 1 MiB
    float*  s1g = (float*)(ws + (1 << 20));
    float*  e1g = s1g + NN;
    float*  f1g = e1g + NN;
    float*  s2g = f1g + NN;
    float*  e2g = s2g + NN;
    float*  f2g = e2g + NN;
    float*  pacc = f2g + NN;                        // 2*8192*64 fp32 = 4 MiB
    float*  prs  = pacc + 2 * NN * FOUT;            // 2*8192 fp32

    gat_h_kernel<<<NN / 32, 256, 0, stream>>>(input, W, a, hT,
                                              s1g, e1g, f1g, s2g, e2g, f2g);
    dim3 gridB(NN / 32, 2);
    gat_att_kernel<<<gridB, 256, 0, stream>>>(adj, hT,
                                              s1g, e1g, f1g, s2g, e2g, f2g,
                                              pacc, prs);
    gat_combine_kernel<<<NN * FOUT / 4 / 256, 256, 0, stream>>>(pacc, prs, out);
}